// Round 2
// baseline (243.250 us; speedup 1.0000x reference)
//
#include <hip/hip_runtime.h>
#include <stdint.h>

// SE block, float32: x[32,256,56,56] -> out = x * sigmoid(MLP(mean_hw(x)))
// B=32, CH=256, BOT=32, HW=56*56=3136
#define BATCH 32
#define CH    256
#define BOT   32
#define HW    3136
#define CHUNKS_PER_PLANE 784          // HW / 4 floats per float4
#define TOTAL_CHUNKS (BATCH * CH * CHUNKS_PER_PLANE)  // 6,422,528

// ---------------- Kernel A: global average pool ----------------
// One wave (64 lanes) per (b,c) plane; block = 4 waves = 4 planes.
// grid = 8192/4 = 2048 blocks. Plane = 784 float4 chunks, base 16B-aligned
// (3136*4 bytes = 12544, multiple of 16).
__global__ __launch_bounds__(256) void pool_kernel(
        const float* __restrict__ x, float* __restrict__ s_out) {
    const int wave = threadIdx.x >> 6;
    const int lane = threadIdx.x & 63;
    const int bc = blockIdx.x * 4 + wave;   // < 8192

    const float4* p4 = (const float4*)(x + (size_t)bc * HW);
    float sum = 0.f;
    #pragma unroll
    for (int i = 0; i < 13; ++i) {          // 13*64 = 832 >= 784
        int idx = lane + i * 64;
        if (idx < CHUNKS_PER_PLANE) {
            float4 v = p4[idx];
            sum += (v.x + v.y) + (v.z + v.w);
        }
    }
    // wave-level reduce (width 64)
    #pragma unroll
    for (int off = 32; off > 0; off >>= 1)
        sum += __shfl_down(sum, off, 64);
    if (lane == 0) s_out[bc] = sum * (1.0f / (float)HW);
}

// ---------------- Kernel B: tiny MLP ----------------
// Single block, 256 threads. s[32,256] -> h[32,32] (relu) -> g[32,256] (sigmoid)
__global__ __launch_bounds__(256) void mlp_kernel(
        const float* __restrict__ s,
        const float* __restrict__ w1, const float* __restrict__ b1,
        const float* __restrict__ w2, const float* __restrict__ b2,
        float* __restrict__ g) {
    __shared__ float hs[BATCH][BOT];
    const int t = threadIdx.x;

    // h[b][o] = relu(b1[o] + sum_c s[b][c] * w1[o][c]);  1024 entries, 4/thread
    for (int i = t; i < BATCH * BOT; i += 256) {
        const int b = i >> 5;      // /BOT
        const int o = i & 31;      // %BOT
        const float* srow = s  + b * CH;
        const float* wrow = w1 + o * CH;
        float acc = b1[o];
        #pragma unroll 8
        for (int c = 0; c < CH; ++c)
            acc = fmaf(srow[c], wrow[c], acc);
        hs[b][o] = fmaxf(acc, 0.f);
    }
    __syncthreads();

    // g[b][c] = sigmoid(b2[c] + sum_o h[b][o] * w2[c][o]);  8192 entries, 32/thread
    for (int i = t; i < BATCH * CH; i += 256) {
        const int b = i >> 8;      // /CH
        const int c = i & 255;     // %CH
        const float* wrow = w2 + c * BOT;
        float acc = b2[c];
        #pragma unroll
        for (int o = 0; o < BOT; ++o)
            acc = fmaf(hs[b][o], wrow[o], acc);
        g[i] = 1.0f / (1.0f + __expf(-acc));
    }
}

// ---------------- Kernel C: scale ----------------
// One float4 per thread. grid = TOTAL_CHUNKS/256 = 25088 exactly.
__global__ __launch_bounds__(256) void scale_kernel(
        const float* __restrict__ x, const float* __restrict__ g,
        float* __restrict__ out) {
    const int chunk = blockIdx.x * 256 + threadIdx.x;
    const int bc = chunk / CHUNKS_PER_PLANE;   // compiler emits magic-multiply
    const float gv = g[bc];

    float4 v = ((const float4*)x)[chunk];
    v.x *= gv; v.y *= gv; v.z *= gv; v.w *= gv;
    ((float4*)out)[chunk] = v;
}

extern "C" void kernel_launch(void* const* d_in, const int* in_sizes, int n_in,
                              void* d_out, int out_size, void* d_ws, size_t ws_size,
                              hipStream_t stream) {
    const float* x  = (const float*)d_in[0];
    const float* w1 = (const float*)d_in[1];
    const float* b1 = (const float*)d_in[2];
    const float* w2 = (const float*)d_in[3];
    const float* b2 = (const float*)d_in[4];
    float* out = (float*)d_out;

    float* s = (float*)d_ws;              // 8192 floats = 32 KB
    float* g = s + BATCH * CH;            // 8192 floats = 32 KB

    pool_kernel <<<BATCH * CH / 4, 256, 0, stream>>>(x, s);
    mlp_kernel  <<<1, 256, 0, stream>>>(s, w1, b1, w2, b2, g);
    scale_kernel<<<TOTAL_CHUNKS / 256, 256, 0, stream>>>(x, g, out);
}